// Round 1
// baseline (139.833 us; speedup 1.0000x reference)
//
#include <hip/hip_runtime.h>

#define DIM 128
#define NUM_NEG 20
#define BATCH 16384
#define INV_T (1.0f / 0.07f)

// One 64-lane wave per batch element. Each lane holds float2 of the target
// row; 21 gathered rows -> dot via 2 FMA + 6-step shfl_xor reduce.
// 4 waves/block -> LDS partial -> one atomicAdd per block (4096 atomics,
// avoids same-address serialization of 16384 per-wave atomics).
__global__ __launch_bounds__(256) void infonce_kernel(
    const float* __restrict__ emb,
    const int* __restrict__ targets,
    const int* __restrict__ contexts,
    const int* __restrict__ negatives,
    float* __restrict__ out)
{
    __shared__ float block_part[4];
    const int lane = threadIdx.x & 63;
    const int wave_in_block = threadIdx.x >> 6;
    const int b = blockIdx.x * 4 + wave_in_block;

    float loss = 0.0f;
    if (b < BATCH) {
        const int t_idx = targets[b];
        const float2 tv =
            *reinterpret_cast<const float2*>(emb + (size_t)t_idx * DIM + lane * 2);

        float scores[NUM_NEG + 1];
        {
            const int c_idx = contexts[b];
            const float2 v =
                *reinterpret_cast<const float2*>(emb + (size_t)c_idx * DIM + lane * 2);
            float p = tv.x * v.x + tv.y * v.y;
            #pragma unroll
            for (int off = 32; off; off >>= 1) p += __shfl_xor(p, off);
            scores[0] = p * INV_T;
        }
        #pragma unroll
        for (int k = 0; k < NUM_NEG; ++k) {
            const int n_idx = negatives[b * NUM_NEG + k];
            const float2 v =
                *reinterpret_cast<const float2*>(emb + (size_t)n_idx * DIM + lane * 2);
            float p = tv.x * v.x + tv.y * v.y;
            #pragma unroll
            for (int off = 32; off; off >>= 1) p += __shfl_xor(p, off);
            scores[k + 1] = p * INV_T;
        }

        // logsumexp over 21 scores (uniform across lanes after full reduce)
        float m = scores[0];
        #pragma unroll
        for (int i = 1; i <= NUM_NEG; ++i) m = fmaxf(m, scores[i]);
        float s = 0.0f;
        #pragma unroll
        for (int i = 0; i <= NUM_NEG; ++i) s += expf(scores[i] - m);
        // -log_softmax[0] = logsumexp - scores[0]
        loss = (m + logf(s) - scores[0]) * (1.0f / BATCH);
    }

    if (lane == 0) block_part[wave_in_block] = loss;
    __syncthreads();
    if (threadIdx.x == 0) {
        atomicAdd(out, block_part[0] + block_part[1] + block_part[2] + block_part[3]);
    }
}

extern "C" void kernel_launch(void* const* d_in, const int* in_sizes, int n_in,
                              void* d_out, int out_size, void* d_ws, size_t ws_size,
                              hipStream_t stream) {
    const float* emb       = (const float*)d_in[0];
    const int*   targets   = (const int*)d_in[1];
    const int*   contexts  = (const int*)d_in[2];
    const int*   negatives = (const int*)d_in[3];
    float* out = (float*)d_out;

    // d_out is re-poisoned to 0xAA before every launch — zero it on-stream.
    hipMemsetAsync(out, 0, sizeof(float), stream);

    infonce_kernel<<<dim3(BATCH / 4), dim3(256), 0, stream>>>(
        emb, targets, contexts, negatives, out);
}

// Round 2
// 139.516 us; speedup vs baseline: 1.0023x; 1.0023x over previous
//
#include <hip/hip_runtime.h>
#include <math.h>

#define DIM 128
#define NUM_NEG 20
#define BATCH 16384
#define INV_T (1.0f / 0.07f)
#define NROWS 21  // 1 positive (context) + 20 negatives

// One 64-lane wave per batch element, but split as 4 groups x 16 lanes.
// Each lane holds 8 floats (2 x float4) of the target row. Per iteration the
// 4 groups gather 4 different score rows (512 B coalesced each), dot with
// 8 FMAs, and reduce across 16 lanes in 4 shfl_xor steps. 6 iterations cover
// all 21 rows. Logsumexp: each lane folds its 6 scores locally (6 expf), then
// a 2-step (m,s) merge across the 4 groups.
__global__ __launch_bounds__(256) void infonce_kernel(
    const float* __restrict__ emb,
    const int* __restrict__ targets,
    const int* __restrict__ contexts,
    const int* __restrict__ negatives,
    float* __restrict__ out)
{
    __shared__ float block_part[4];
    const int lane = threadIdx.x & 63;
    const int wib  = threadIdx.x >> 6;   // wave in block
    const int b    = blockIdx.x * 4 + wib;
    const int sub  = lane & 15;          // 8-float chunk within the row
    const int grp  = lane >> 4;          // row-group 0..3

    const int t_idx = targets[b];
    const float4* tp =
        reinterpret_cast<const float4*>(emb + (size_t)t_idx * DIM + sub * 8);
    const float4 t0 = tp[0];
    const float4 t1 = tp[1];

    float score[6];
    #pragma unroll
    for (int it = 0; it < 6; ++it) {
        const int r = it * 4 + grp;      // row id 0..23 (21..23 invalid)
        float sc = -INFINITY;
        if (r < NROWS) {
            const int node = (r == 0) ? contexts[b]
                                      : negatives[b * NUM_NEG + (r - 1)];
            const float4* vp = reinterpret_cast<const float4*>(
                emb + (size_t)node * DIM + sub * 8);
            const float4 v0 = vp[0];
            const float4 v1 = vp[1];
            float p = t0.x * v0.x + t0.y * v0.y + t0.z * v0.z + t0.w * v0.w
                    + t1.x * v1.x + t1.y * v1.y + t1.z * v1.z + t1.w * v1.w;
            // reduce across the 16 lanes of this group (masks < 16 stay in-group)
            p += __shfl_xor(p, 1);
            p += __shfl_xor(p, 2);
            p += __shfl_xor(p, 4);
            p += __shfl_xor(p, 8);
            sc = p * INV_T;
        }
        score[it] = sc;
    }

    // per-lane logsumexp over its 6 scores (invalid slots are -inf -> exp = 0)
    float m = score[0];
    #pragma unroll
    for (int i = 1; i < 6; ++i) m = fmaxf(m, score[i]);
    float s = 0.0f;
    #pragma unroll
    for (int i = 0; i < 6; ++i) s += expf(score[i] - m);

    // merge (m, s) across the 4 groups: masks 16 and 32
    #pragma unroll
    for (int mask = 16; mask <= 32; mask <<= 1) {
        const float mo = __shfl_xor(m, mask);
        const float so = __shfl_xor(s, mask);
        const float mn = fmaxf(m, mo);
        s = s * expf(m - mn) + so * expf(mo - mn);
        m = mn;
    }

    // positive score is row 0 = group 0, iteration 0 -> lane 0's score[0]
    const float pos = __shfl(score[0], 0);
    const float loss = (m + logf(s) - pos) * (1.0f / BATCH);

    if (lane == 0) block_part[wib] = loss;
    __syncthreads();
    if (threadIdx.x == 0) {
        atomicAdd(out, block_part[0] + block_part[1] +
                       block_part[2] + block_part[3]);
    }
}

extern "C" void kernel_launch(void* const* d_in, const int* in_sizes, int n_in,
                              void* d_out, int out_size, void* d_ws, size_t ws_size,
                              hipStream_t stream) {
    const float* emb       = (const float*)d_in[0];
    const int*   targets   = (const int*)d_in[1];
    const int*   contexts  = (const int*)d_in[2];
    const int*   negatives = (const int*)d_in[3];
    float* out = (float*)d_out;

    // d_out is re-poisoned to 0xAA before every launch — zero it on-stream.
    hipMemsetAsync(out, 0, sizeof(float), stream);

    infonce_kernel<<<dim3(BATCH / 4), dim3(256), 0, stream>>>(
        emb, targets, contexts, negatives, out);
}